// Round 1
// baseline (921.431 us; speedup 1.0000x reference)
//
#include <hip/hip_runtime.h>
#include <cstdint>
#include <cstddef>

// Problem constants
#define B_  512
#define T_  256
#define D_  256
#define H_  1024
#define K2  512      // effective K = 2*D (x_tilde | m); xm middle third folded into cvec
#define N2  2048     // stacked outputs: [0,1024)=z preact, [1024,2048)=h_til preact
#define TC  32       // timesteps per chunk
#define NCHUNK 8     // TC*NCHUNK == T_

// Workspace layout (bytes). Total ~88 MB.
#define OFF_WB    ((size_t)0)                      // bf16 [2048][512]            2 MB
#define OFF_CVEC  ((size_t)2097152)                // f32  [2048]                 8 KB
#define OFF_H     ((size_t)2105344)                // f32  [B][H]                 2 MB
#define OFF_INP2  ((size_t)4202496)                // bf16 [TC*B][512]           16 MB
#define OFF_GATES ((size_t)20979712)               // bf16 [TC*B][2048]          64 MB

typedef short   bf16x8 __attribute__((ext_vector_type(8)));   // 8 bf16 (4 VGPRs)
typedef float   f32x4  __attribute__((ext_vector_type(4)));

__device__ __forceinline__ unsigned short f2bf(float f) {
    unsigned int u = __float_as_uint(f);
    u += 0x7fffu + ((u >> 16) & 1u);   // round-to-nearest-even
    return (unsigned short)(u >> 16);
}
__device__ __forceinline__ float bf2f(unsigned short s) {
    return __uint_as_float(((unsigned int)s) << 16);
}
__device__ __forceinline__ void async16(const void* g, void* l) {
    __builtin_amdgcn_global_load_lds(
        (const __attribute__((address_space(1))) void*)g,
        (__attribute__((address_space(3))) void*)l, 16, 0, 0);
}

// ---- Prep: pack effective weight columns [0:D) and [2D:3D) to bf16 [2048][512] ----
__global__ void build_wb(const float* __restrict__ Wz, const float* __restrict__ Wh,
                         unsigned short* __restrict__ Wb) {
    int e = blockIdx.x * 256 + threadIdx.x;        // 2048*512/... one elem each
    int r = e >> 9;
    int k = e & 511;
    int col = (k < D_) ? k : (k + D_);             // skip the xm middle third
    float v = (r < H_) ? Wz[(size_t)r * 768 + col]
                       : Wh[(size_t)(r - H_) * 768 + col];
    Wb[e] = f2bf(v);
}

// ---- Prep: cvec[r] = bias[r] + W[r, D:2D] . xm ----
__global__ void build_cvec(const float* __restrict__ Wz, const float* __restrict__ bz,
                           const float* __restrict__ Wh, const float* __restrict__ bh,
                           const float* __restrict__ xm, float* __restrict__ cvec) {
    int r = blockIdx.x;           // 0..2047
    int d = threadIdx.x;          // 0..255
    const float* W = (r < H_) ? (Wz + (size_t)r * 768) : (Wh + (size_t)(r - H_) * 768);
    float v = W[D_ + d] * xm[d];
    for (int off = 32; off; off >>= 1) v += __shfl_down(v, off);
    __shared__ float red[4];
    if ((d & 63) == 0) red[d >> 6] = v;
    __syncthreads();
    if (d == 0) {
        float bias = (r < H_) ? bz[r] : bh[r - H_];
        cvec[r] = bias + red[0] + red[1] + red[2] + red[3];
    }
}

// ---- Per-chunk: build bf16 inp2 rows (r = tc*B + b): [x_tilde(0:256) | m(0:256)] ----
__global__ void build_inp2(const float* __restrict__ X, const float* __restrict__ Mm,
                           const float* __restrict__ xm, const float* __restrict__ gx,
                           unsigned short* __restrict__ inp2, int chunk) {
    int g = blockIdx.x * 256 + threadIdx.x;        // vec8 id; total TC*B*64
    int r = g >> 6;
    int k = (g & 63) * 8;
    int tc = r >> 9;
    int b  = r & (B_ - 1);
    int t  = chunk * TC + tc;
    unsigned short o[8];
    if (k < D_) {
        int d = k;
        const float4* xp = (const float4*)(X  + ((size_t)b * T_ + t) * D_ + d);
        const float4* mp = (const float4*)(Mm + ((size_t)b * T_ + t) * D_ + d);
        float xs[8], ms[8];
        float4 v;
        v = xp[0]; xs[0]=v.x; xs[1]=v.y; xs[2]=v.z; xs[3]=v.w;
        v = xp[1]; xs[4]=v.x; xs[5]=v.y; xs[6]=v.z; xs[7]=v.w;
        v = mp[0]; ms[0]=v.x; ms[1]=v.y; ms[2]=v.z; ms[3]=v.w;
        v = mp[1]; ms[4]=v.x; ms[5]=v.y; ms[6]=v.z; ms[7]=v.w;
        #pragma unroll
        for (int j = 0; j < 8; j++) {
            float m = ms[j], x = xs[j], mu = xm[d + j], gg = gx[d + j];
            float xh = m * x + (1.f - m) * mu;
            float gd = __expf(-gg * (1.f - m));
            o[j] = f2bf(gd * xh + (1.f - gd) * mu);
        }
    } else {
        int d = k - D_;
        const float4* mp = (const float4*)(Mm + ((size_t)b * T_ + t) * D_ + d);
        float4 m0 = mp[0], m1 = mp[1];
        o[0]=f2bf(m0.x); o[1]=f2bf(m0.y); o[2]=f2bf(m0.z); o[3]=f2bf(m0.w);
        o[4]=f2bf(m1.x); o[5]=f2bf(m1.y); o[6]=f2bf(m1.z); o[7]=f2bf(m1.w);
    }
    uint4 pk;
    pk.x = (unsigned)o[0] | ((unsigned)o[1] << 16);
    pk.y = (unsigned)o[2] | ((unsigned)o[3] << 16);
    pk.z = (unsigned)o[4] | ((unsigned)o[5] << 16);
    pk.w = (unsigned)o[6] | ((unsigned)o[7] << 16);
    *(uint4*)(inp2 + (size_t)r * K2 + k) = pk;
}

// ---- GEMM: gates[r][n] = act(inp2[r,:] . Wb[n,:] + cvec[n]) ----
// m97-style: 128x128 tile, BK=32, global_load_lds width=16, 16x16x32 bf16 MFMA.
// grid = (Mrows/128, 16); tn<8 -> sigmoid (z), tn>=8 -> tanh (h_til).
__global__ __launch_bounds__(256) void gemm_gates(
    const unsigned short* __restrict__ A,      // [TC*B][512] bf16
    const unsigned short* __restrict__ W,      // [2048][512] bf16
    const float* __restrict__ cvec,            // [2048]
    unsigned short* __restrict__ gates)        // [TC*B][2048] bf16
{
    __shared__ __align__(16) unsigned short As[128 * 32];
    __shared__ __align__(16) unsigned short Bs[128 * 32];
    const int tid  = threadIdx.x;
    const int lane = tid & 63;
    const int w    = tid >> 6;
    const int tm = blockIdx.x, tn = blockIdx.y;
    const int wm = w & 1, wn = w >> 1;

    // staging: 8 segments of 16 rows x 32 cols (1 KB each); wave w does segs {2w, 2w+1}
    const int seg  = w * 2;
    const int srow = seg * 16 + (lane >> 2);
    const int scol = (lane & 3) * 8;
    const unsigned short* aptr = A + (size_t)(tm * 128 + srow) * K2 + scol;
    const unsigned short* bptr = W + (size_t)(tn * 128 + srow) * K2 + scol;
    unsigned short* adst = &As[seg * 16 * 32];
    unsigned short* bdst = &Bs[seg * 16 * 32];

    f32x4 acc[4][4] = {};

    for (int k0 = 0; k0 < K2; k0 += 32) {
        __syncthreads();
        async16(aptr + k0,           adst);
        async16(aptr + 16*K2 + k0,   adst + 16*32);
        async16(bptr + k0,           bdst);
        async16(bptr + 16*K2 + k0,   bdst + 16*32);
        __syncthreads();   // compiler drains vmcnt before s_barrier
        bf16x8 af[4], bf[4];
        #pragma unroll
        for (int i = 0; i < 4; i++)
            af[i] = *(const bf16x8*)&As[(wm*64 + i*16 + (lane & 15)) * 32 + (lane >> 4) * 8];
        #pragma unroll
        for (int j = 0; j < 4; j++)
            bf[j] = *(const bf16x8*)&Bs[(wn*64 + j*16 + (lane & 15)) * 32 + (lane >> 4) * 8];
        #pragma unroll
        for (int i = 0; i < 4; i++)
            #pragma unroll
            for (int j = 0; j < 4; j++)
                acc[i][j] = __builtin_amdgcn_mfma_f32_16x16x32_bf16(af[i], bf[j], acc[i][j], 0, 0, 0);
    }

    const bool is_z = (tn < 8);    // wave-uniform: which activation
    #pragma unroll
    for (int j = 0; j < 4; j++) {
        const int ncol = tn*128 + wn*64 + j*16 + (lane & 15);
        const float cadd = cvec[ncol];
        #pragma unroll
        for (int i = 0; i < 4; i++) {
            const int mbase = tm*128 + wm*64 + i*16 + (lane >> 4) * 4;
            #pragma unroll
            for (int r = 0; r < 4; r++) {
                float v = acc[i][j][r] + cadd;
                if (is_z) v = 1.f / (1.f + __expf(-v));
                else      v = 2.f / (1.f + __expf(-2.f * v)) - 1.f;
                gates[(size_t)(mbase + r) * N2 + ncol] = f2bf(v);
            }
        }
    }
}

// ---- Per-chunk elementwise scan: h = (1-z)*h + z*h_til over TC steps ----
__global__ void recurrence(const unsigned short* __restrict__ gates,
                           float* __restrict__ hbuf, int first) {
    const int g  = blockIdx.x * 256 + threadIdx.x;   // B*H/2 threads
    const int b  = g >> 9;
    const int nb = (g & 511) * 2;
    float h0, h1;
    if (first) { h0 = 0.f; h1 = 0.f; }
    else { float2 hv = *(const float2*)&hbuf[(size_t)b * H_ + nb]; h0 = hv.x; h1 = hv.y; }
    for (int tc = 0; tc < TC; tc++) {
        const unsigned short* base = gates + (size_t)(tc * B_ + b) * N2;
        unsigned int zz = *(const unsigned int*)(base + nb);
        unsigned int hh = *(const unsigned int*)(base + H_ + nb);
        float z0 = bf2f((unsigned short)(zz & 0xffff));
        float z1 = bf2f((unsigned short)(zz >> 16));
        float t0 = bf2f((unsigned short)(hh & 0xffff));
        float t1 = bf2f((unsigned short)(hh >> 16));
        h0 = (1.f - z0) * h0 + z0 * t0;
        h1 = (1.f - z1) * h1 + z1 * t1;
    }
    *(float2*)&hbuf[(size_t)b * H_ + nb] = make_float2(h0, h1);
}

// ---- Output head: out[b] = sigmoid(h[b,:] . Wout + bout) ----
__global__ void head(const float* __restrict__ hbuf, const float* __restrict__ Wout,
                     const float* __restrict__ bout, float* __restrict__ out) {
    int b = blockIdx.x;
    float s = 0.f;
    for (int n = threadIdx.x; n < H_; n += 256)
        s += hbuf[(size_t)b * H_ + n] * Wout[n];
    for (int off = 32; off; off >>= 1) s += __shfl_down(s, off);
    __shared__ float red[4];
    if ((threadIdx.x & 63) == 0) red[threadIdx.x >> 6] = s;
    __syncthreads();
    if (threadIdx.x == 0) {
        float t = red[0] + red[1] + red[2] + red[3] + bout[0];
        out[b] = 1.f / (1.f + expf(-t));
    }
}

extern "C" void kernel_launch(void* const* d_in, const int* in_sizes, int n_in,
                              void* d_out, int out_size, void* d_ws, size_t ws_size,
                              hipStream_t stream) {
    const float* X    = (const float*)d_in[0];
    const float* Mm   = (const float*)d_in[1];
    const float* xm   = (const float*)d_in[2];
    const float* gx   = (const float*)d_in[3];
    const float* Wz   = (const float*)d_in[4];
    const float* bz   = (const float*)d_in[5];
    // d_in[6]=Wr, d_in[7]=br: dead code in reference (r_t unused) — skipped
    const float* Wh   = (const float*)d_in[8];
    const float* bh   = (const float*)d_in[9];
    const float* Wout = (const float*)d_in[10];
    const float* bout = (const float*)d_in[11];
    float* out = (float*)d_out;

    char* ws = (char*)d_ws;
    unsigned short* Wb    = (unsigned short*)(ws + OFF_WB);
    float*          cvec  = (float*)(ws + OFF_CVEC);
    float*          hbuf  = (float*)(ws + OFF_H);
    unsigned short* inp2  = (unsigned short*)(ws + OFF_INP2);
    unsigned short* gates = (unsigned short*)(ws + OFF_GATES);

    build_wb  <<<dim3(N2 * K2 / 256), dim3(256), 0, stream>>>(Wz, Wh, Wb);
    build_cvec<<<dim3(N2),            dim3(256), 0, stream>>>(Wz, bz, Wh, bh, xm, cvec);

    for (int c = 0; c < NCHUNK; c++) {
        build_inp2<<<dim3(TC * B_ * 64 / 256), dim3(256), 0, stream>>>(X, Mm, xm, gx, inp2, c);
        gemm_gates<<<dim3(TC * B_ / 128, 16),  dim3(256), 0, stream>>>(inp2, Wb, cvec, gates);
        recurrence<<<dim3(B_ * H_ / 2 / 256),  dim3(256), 0, stream>>>(gates, hbuf, c == 0 ? 1 : 0);
    }

    head<<<dim3(B_), dim3(256), 0, stream>>>(hbuf, Wout, bout, out);
}